// Round 1
// baseline (718.539 us; speedup 1.0000x reference)
//
#include <hip/hip_runtime.h>
#include <hip/hip_bf16.h>

#define VOCAB 33
#define EMBD  16
#define HID   128
#define TSTEP 14
#define BROWS 64   // batch rows per block
#define KCOMB 160  // 128 (h) + 16 (emb) + 16 (zero pad)

typedef __attribute__((ext_vector_type(8))) short bf16x8;
typedef __attribute__((ext_vector_type(4))) float f32x4;

#define MFMA(a,b,c) __builtin_amdgcn_mfma_f32_16x16x32_bf16((a),(b),(c),0,0,0)

__device__ inline ushort f2b(float f){
  union { float f; unsigned u; } v; v.f = f;
  unsigned r = v.u + 0x7fff + ((v.u >> 16) & 1);   // RNE to bf16
  return (ushort)(r >> 16);
}
__device__ inline float sigm(float x){ return 1.f / (1.f + __expf(-x)); }
__device__ inline float tanh_fast(float x){ float e = __expf(2.f*x); return 1.f - 2.f/(e + 1.f); }

// ---- prep: bf16 weight repack -------------------------------------------
// wcomb[n][k], n<512, k<160: k<128 -> W_hh[n][k]; k<144 -> W_ih[n][k-128]; else 0
__global__ void prep_kernel(const float* __restrict__ W_ih, const float* __restrict__ W_hh,
                            const float* __restrict__ W1,   const float* __restrict__ W2,
                            ushort* __restrict__ wcomb, ushort* __restrict__ w1b, ushort* __restrict__ w2b){
  int i = blockIdx.x * blockDim.x + threadIdx.x;
  if (i < 512*KCOMB){
    int n = i / KCOMB, k = i - n*KCOMB;
    float v = (k < 128) ? W_hh[n*128 + k] : ((k < 144) ? W_ih[n*16 + (k-128)] : 0.f);
    wcomb[i] = f2b(v);
  } else if (i < 512*KCOMB + 64*128){
    int j = i - 512*KCOMB;
    w1b[j] = f2b(W1[j]);
  } else if (i < 512*KCOMB + 64*128 + 32*64){
    int j = i - 512*KCOMB - 64*128;
    w2b[j] = f2b(W2[j]);
  }
}

// ---- main fused kernel ---------------------------------------------------
__global__ __launch_bounds__(512, 2)
void lstm_kernel(const int* __restrict__ x, const float* __restrict__ emb_table,
                 const float* __restrict__ b_ih, const float* __restrict__ b_hh,
                 const float* __restrict__ b1, const float* __restrict__ b2,
                 const float* __restrict__ W3, const float* __restrict__ b3,
                 const ushort* __restrict__ wcomb, const ushort* __restrict__ w1b,
                 const ushort* __restrict__ w2b, float* __restrict__ out)
{
  __shared__ ushort A_h[BROWS*128];            // h state, bf16, XOR-swizzled rows
  __shared__ ushort E[TSTEP*BROWS*EMBD];       // all timesteps' embeddings, bf16
  __shared__ __align__(16) ushort zerobuf[16];
  __shared__ ushort y1[BROWS*64];              // MLP layer-1 out, bf16, swizzled
  __shared__ float  y2[BROWS*33];              // MLP layer-2 out, fp32, padded

  const int tid  = threadIdx.x;
  const int lane = tid & 63;
  const int w    = tid >> 6;      // wave 0..7
  const int l15  = lane & 15;
  const int lg   = lane >> 4;     // 0..3 (k-group)
  const int r0   = blockIdx.x * BROWS;

  // --- zero init: h state + zerobuf ---
  { int* az = (int*)A_h;
    for (int i = tid; i < BROWS*128/2; i += 512) az[i] = 0;
    if (tid < 8) ((int*)zerobuf)[tid] = 0; }

  // --- stage all timesteps' embeddings (padding_idx=0 -> zeros) ---
  for (int idx = tid; idx < BROWS*TSTEP; idx += 512){
    int r = idx / TSTEP, t = idx - r*TSTEP;
    int tok = x[(r0 + r)*TSTEP + t];
    ushort* dst = E + (t*BROWS + r)*EMBD;
    if (tok == 0){
      #pragma unroll
      for (int e = 0; e < EMBD; ++e) dst[e] = 0;
    } else {
      const float* src = emb_table + tok*EMBD;
      #pragma unroll
      for (int e = 0; e < EMBD; ++e) dst[e] = f2b(src[e]);
    }
  }

  // --- load persistent B fragments: Wcomb[n][k], n = g*128 + w*16 + l15 ---
  bf16x8 bB[4][5];
  #pragma unroll
  for (int g = 0; g < 4; ++g){
    const int n = g*128 + w*16 + l15;
    #pragma unroll
    for (int kt = 0; kt < 5; ++kt)
      bB[g][kt] = *(const bf16x8*)((const short*)wcomb + n*KCOMB + kt*32 + lg*8);
  }

  // --- per-gate bias (depends only on col = l15 per gate block) ---
  float bias[4];
  #pragma unroll
  for (int g = 0; g < 4; ++g){
    const int n = g*128 + w*16 + l15;
    bias[g] = b_ih[n] + b_hh[n];
  }

  // --- cell state fp32 in registers: rows (m*16 + lg*4 + r), col w*16+l15 ---
  f32x4 cst[4];
  #pragma unroll
  for (int m = 0; m < 4; ++m) cst[m] = (f32x4){0.f,0.f,0.f,0.f};

  const int j2 = w*16 + l15;   // this lane's hidden column

  // ================= recurrence =================
  for (int t = 0; t < TSTEP; ++t){
    __syncthreads();   // h (and on t=0: E, zero-init) visible

    f32x4 acc[4][4];
    #pragma unroll
    for (int g = 0; g < 4; ++g)
      #pragma unroll
      for (int m = 0; m < 4; ++m)
        acc[g][m] = (f32x4){bias[g],bias[g],bias[g],bias[g]};

    #pragma unroll
    for (int m = 0; m < 4; ++m){
      const int row = m*16 + l15;
      const int swz = (row & 7) << 3;
      const short* abase = (const short*)A_h + row*128;
      bf16x8 aF[5];
      #pragma unroll
      for (int kt = 0; kt < 4; ++kt)
        aF[kt] = *(const bf16x8*)(abase + ((kt*32 + lg*8) ^ swz));
      { // k-tile 4: [emb(16) | 0(16)]
        const short* eptr = (lg < 2)
            ? ((const short*)E + (t*BROWS + row)*EMBD + lg*8)
            : (const short*)zerobuf;
        aF[4] = *(const bf16x8*)eptr;
      }
      #pragma unroll
      for (int g = 0; g < 4; ++g)
        #pragma unroll
        for (int kt = 0; kt < 5; ++kt)
          acc[g][m] = MFMA(aF[kt], bB[g][kt], acc[g][m]);
    }

    __syncthreads();   // all reads of A_h done before overwrite

    ushort* ah = (ushort*)A_h;
    #pragma unroll
    for (int m = 0; m < 4; ++m){
      #pragma unroll
      for (int r = 0; r < 4; ++r){
        const int row = m*16 + lg*4 + r;
        float iv = sigm(acc[0][m][r]);
        float fv = sigm(acc[1][m][r]);
        float gv = tanh_fast(acc[2][m][r]);
        float ov = sigm(acc[3][m][r]);
        float cv = fv*cst[m][r] + iv*gv;
        cst[m][r] = cv;
        float hv = ov * tanh_fast(cv);
        ah[row*128 + (j2 ^ ((row & 7) << 3))] = f2b(hv);
      }
    }
  }

  __syncthreads();  // h_last in A_h ready

  // ================= MLP head =================
  // layer 1: [64x128] @ W1^T[128x64] -> sigmoid -> y1 (bf16, swizzled)
  {
    const int mt = w & 3, nh = w >> 2;
    f32x4 acc1[2];
    #pragma unroll
    for (int nt = 0; nt < 2; ++nt){
      float bv = b1[nh*32 + nt*16 + l15];
      acc1[nt] = (f32x4){bv,bv,bv,bv};
    }
    const int arow = mt*16 + l15;
    const int aswz = (arow & 7) << 3;
    const short* abase = (const short*)A_h + arow*128;
    #pragma unroll
    for (int kt = 0; kt < 4; ++kt){
      bf16x8 aF = *(const bf16x8*)(abase + ((kt*32 + lg*8) ^ aswz));
      #pragma unroll
      for (int nt = 0; nt < 2; ++nt){
        const int n = nh*32 + nt*16 + l15;
        bf16x8 bF = *(const bf16x8*)((const short*)w1b + n*128 + kt*32 + lg*8);
        acc1[nt] = MFMA(aF, bF, acc1[nt]);
      }
    }
    #pragma unroll
    for (int nt = 0; nt < 2; ++nt)
      #pragma unroll
      for (int r = 0; r < 4; ++r){
        const int row = mt*16 + lg*4 + r;
        const int col = nh*32 + nt*16 + l15;
        y1[row*64 + (col ^ ((row & 7) << 3))] = f2b(sigm(acc1[nt][r]));
      }
  }
  __syncthreads();

  // layer 2: [64x64] @ W2^T[64x32] -> sigmoid -> y2 (fp32, padded 33)
  if (w < 4){
    f32x4 acc2[2];
    #pragma unroll
    for (int nt = 0; nt < 2; ++nt){
      float bv = b2[nt*16 + l15];
      acc2[nt] = (f32x4){bv,bv,bv,bv};
    }
    const int arow = w*16 + l15;
    const int aswz = (arow & 7) << 3;
    const short* abase = (const short*)y1 + arow*64;
    #pragma unroll
    for (int kt = 0; kt < 2; ++kt){
      bf16x8 aF = *(const bf16x8*)(abase + ((kt*32 + lg*8) ^ aswz));
      #pragma unroll
      for (int nt = 0; nt < 2; ++nt){
        const int n = nt*16 + l15;
        bf16x8 bF = *(const bf16x8*)((const short*)w2b + n*64 + kt*32 + lg*8);
        acc2[nt] = MFMA(aF, bF, acc2[nt]);
      }
    }
    #pragma unroll
    for (int nt = 0; nt < 2; ++nt)
      #pragma unroll
      for (int r = 0; r < 4; ++r){
        const int row = w*16 + lg*4 + r;
        const int col = nt*16 + l15;
        y2[row*33 + col] = sigm(acc2[nt][r]);
      }
  }
  __syncthreads();

  // layer 3: [64x32] @ W3^T[32x2] + b3, fp32 vector
  if (tid < 128){
    const int lr = tid >> 1, oc = tid & 1;
    float s = b3[oc];
    #pragma unroll
    for (int k = 0; k < 32; ++k)
      s += y2[lr*33 + k] * W3[oc*32 + k];
    out[(size_t)(r0 + lr)*2 + oc] = s;
  }
}

extern "C" void kernel_launch(void* const* d_in, const int* in_sizes, int n_in,
                              void* d_out, int out_size, void* d_ws, size_t ws_size,
                              hipStream_t stream){
  const int*   x    = (const int*)  d_in[0];
  const float* emb  = (const float*)d_in[1];
  const float* W_ih = (const float*)d_in[2];
  const float* W_hh = (const float*)d_in[3];
  const float* b_ih = (const float*)d_in[4];
  const float* b_hh = (const float*)d_in[5];
  const float* W1   = (const float*)d_in[6];
  const float* b1   = (const float*)d_in[7];
  const float* W2   = (const float*)d_in[8];
  const float* b2   = (const float*)d_in[9];
  const float* W3   = (const float*)d_in[10];
  const float* b3   = (const float*)d_in[11];
  float* out = (float*)d_out;

  const int B = in_sizes[0] / TSTEP;

  ushort* wcomb = (ushort*)d_ws;
  ushort* w1b   = wcomb + 512*KCOMB;
  ushort* w2b   = w1b + 64*128;

  const int prep_total = 512*KCOMB + 64*128 + 32*64;
  prep_kernel<<<(prep_total + 255)/256, 256, 0, stream>>>(W_ih, W_hh, W1, W2, wcomb, w1b, w2b);
  lstm_kernel<<<B/BROWS, 512, 0, stream>>>(x, emb, b_ih, b_hh, b1, b2, W3, b3,
                                           wcomb, w1b, w2b, out);
}

// Round 2
// 515.339 us; speedup vs baseline: 1.3943x; 1.3943x over previous
//
#include <hip/hip_runtime.h>
#include <hip/hip_bf16.h>

#define VOCAB 33
#define EMBD  16
#define HID   128
#define TSTEP 14
#define BROWS 64   // batch rows per block
#define KCOMB 160  // 128 (h) + 16 (emb) + 16 (zero pad)

typedef __attribute__((ext_vector_type(8))) short bf16x8;
typedef __attribute__((ext_vector_type(4))) float f32x4;

#define MFMA(a,b,c) __builtin_amdgcn_mfma_f32_16x16x32_bf16((a),(b),(c),0,0,0)

__device__ inline ushort f2b(float f){
  union { float f; unsigned u; } v; v.f = f;
  unsigned r = v.u + 0x7fff + ((v.u >> 16) & 1);   // RNE to bf16
  return (ushort)(r >> 16);
}
__device__ inline float rcpf(float x){ return __builtin_amdgcn_rcpf(x); }
// fast sigmoid: v_mul + v_exp + v_add + v_rcp (4 instrs, 2 trans)
__device__ inline float sigm(float x){ return rcpf(1.f + __expf(-x)); }
// fast tanh: 1 - 2/(exp(2x)+1)  (5 instrs, 2 trans)
__device__ inline float tanh_fast(float x){
  return __builtin_fmaf(-2.f, rcpf(__expf(2.f*x) + 1.f), 1.f);
}

// ---- prep: bf16 weight repack -------------------------------------------
// wcomb[n][k], n<512, k<160: k<128 -> W_hh[n][k]; k<144 -> W_ih[n][k-128]; else 0
__global__ void prep_kernel(const float* __restrict__ W_ih, const float* __restrict__ W_hh,
                            const float* __restrict__ W1,   const float* __restrict__ W2,
                            ushort* __restrict__ wcomb, ushort* __restrict__ w1b, ushort* __restrict__ w2b){
  int i = blockIdx.x * blockDim.x + threadIdx.x;
  if (i < 512*KCOMB){
    int n = i / KCOMB, k = i - n*KCOMB;
    float v = (k < 128) ? W_hh[n*128 + k] : ((k < 144) ? W_ih[n*16 + (k-128)] : 0.f);
    wcomb[i] = f2b(v);
  } else if (i < 512*KCOMB + 64*128){
    int j = i - 512*KCOMB;
    w1b[j] = f2b(W1[j]);
  } else if (i < 512*KCOMB + 64*128 + 32*64){
    int j = i - 512*KCOMB - 64*128;
    w2b[j] = f2b(W2[j]);
  }
}

// ---- main fused kernel ---------------------------------------------------
__global__ __launch_bounds__(512, 2)
void lstm_kernel(const int* __restrict__ x, const float* __restrict__ emb_table,
                 const float* __restrict__ b_ih, const float* __restrict__ b_hh,
                 const float* __restrict__ b1, const float* __restrict__ b2,
                 const float* __restrict__ W3, const float* __restrict__ b3,
                 const ushort* __restrict__ wcomb, const ushort* __restrict__ w1b,
                 const ushort* __restrict__ w2b, float* __restrict__ out)
{
  __shared__ ushort A_h[2*BROWS*128];            // double-buffered h state, bf16, swizzled
  __shared__ __align__(16) char Ebuf[TSTEP*BROWS*EMBD*2];  // embeddings; head bufs alias after
  __shared__ __align__(16) ushort zerobuf[16];

  ushort* E  = (ushort*)Ebuf;
  ushort* y1 = (ushort*)Ebuf;               // [64][64] bf16, swizzled (head reuse)
  float*  y2 = (float*)(Ebuf + 8192);       // [64][33] fp32, padded   (head reuse)

  const int tid  = threadIdx.x;
  const int lane = tid & 63;
  const int w    = tid >> 6;      // wave 0..7
  const int l15  = lane & 15;
  const int lg   = lane >> 4;     // 0..3 (k-group)
  const int r0   = blockIdx.x * BROWS;

  // --- zero init: h buffer 0 + zerobuf ---
  { int* az = (int*)A_h;
    for (int i = tid; i < BROWS*128/2; i += 512) az[i] = 0;
    if (tid < 8) ((int*)zerobuf)[tid] = 0; }

  // --- stage all timesteps' embeddings (padding_idx=0 -> zeros) ---
  for (int idx = tid; idx < BROWS*TSTEP; idx += 512){
    int r = idx / TSTEP, t = idx - r*TSTEP;
    int tok = x[(r0 + r)*TSTEP + t];
    ushort* dst = E + (t*BROWS + r)*EMBD;
    if (tok == 0){
      #pragma unroll
      for (int e = 0; e < EMBD; ++e) dst[e] = 0;
    } else {
      const float* src = emb_table + tok*EMBD;
      #pragma unroll
      for (int e = 0; e < EMBD; ++e) dst[e] = f2b(src[e]);
    }
  }

  // --- load persistent B fragments: Wcomb[n][k], n = g*128 + w*16 + l15 ---
  bf16x8 bB[4][5];
  #pragma unroll
  for (int g = 0; g < 4; ++g){
    const int n = g*128 + w*16 + l15;
    #pragma unroll
    for (int kt = 0; kt < 5; ++kt)
      bB[g][kt] = *(const bf16x8*)((const short*)wcomb + n*KCOMB + kt*32 + lg*8);
  }

  // --- persistent bias splat: seeds MFMA C operand each step (no init movs) ---
  f32x4 biasv[4];
  #pragma unroll
  for (int g = 0; g < 4; ++g){
    const int n = g*128 + w*16 + l15;
    float bv = b_ih[n] + b_hh[n];
    biasv[g] = (f32x4){bv,bv,bv,bv};
  }

  // --- cell state fp32 in registers: rows (m*16 + lg*4 + r), col w*16+l15 ---
  f32x4 cst[4];
  #pragma unroll
  for (int m = 0; m < 4; ++m) cst[m] = (f32x4){0.f,0.f,0.f,0.f};

  const int j2 = w*16 + l15;   // this lane's hidden column

  __syncthreads();   // zero-init + E visible

  // ================= recurrence (1 barrier/step, double-buffered h) ======
  for (int t = 0; t < TSTEP; ++t){
    const ushort* Ar = A_h + (t & 1)*BROWS*128;
    ushort*       Aw = A_h + ((t & 1)^1)*BROWS*128;

    f32x4 acc[4][4];

    #pragma unroll
    for (int m = 0; m < 4; ++m){
      const int row = m*16 + l15;
      const int swz = (row & 7) << 3;
      const short* abase = (const short*)Ar + row*128;
      bf16x8 aF[5];
      #pragma unroll
      for (int kt = 0; kt < 4; ++kt)
        aF[kt] = *(const bf16x8*)(abase + ((kt*32 + lg*8) ^ swz));
      { // k-tile 4: [emb(16) | 0(16)]
        const short* eptr = (lg < 2)
            ? ((const short*)E + (t*BROWS + row)*EMBD + lg*8)
            : (const short*)zerobuf;
        aF[4] = *(const bf16x8*)eptr;
      }
      #pragma unroll
      for (int g = 0; g < 4; ++g){
        acc[g][m] = MFMA(aF[0], bB[g][0], biasv[g]);   // C = bias splat
        #pragma unroll
        for (int kt = 1; kt < 5; ++kt)
          acc[g][m] = MFMA(aF[kt], bB[g][kt], acc[g][m]);
      }
    }

    #pragma unroll
    for (int m = 0; m < 4; ++m){
      #pragma unroll
      for (int r = 0; r < 4; ++r){
        const int row = m*16 + lg*4 + r;
        float iv = sigm(acc[0][m][r]);
        float fv = sigm(acc[1][m][r]);
        float gv = tanh_fast(acc[2][m][r]);
        float ov = sigm(acc[3][m][r]);
        float cv = fv*cst[m][r] + iv*gv;
        cst[m][r] = cv;
        float hv = ov * tanh_fast(cv);
        Aw[row*128 + (j2 ^ ((row & 7) << 3))] = f2b(hv);
      }
    }

    __syncthreads();   // writes to Aw visible; all reads of Ar complete
  }

  // h_last is in buffer 0 (14 toggles), barrier already passed
  const ushort* Hf = A_h;

  // ================= MLP head =================
  // layer 1: [64x128] @ W1^T[128x64] -> sigmoid -> y1 (bf16, swizzled)
  {
    const int mt = w & 3, nh = w >> 2;
    f32x4 acc1[2];
    #pragma unroll
    for (int nt = 0; nt < 2; ++nt){
      float bv = b1[nh*32 + nt*16 + l15];
      acc1[nt] = (f32x4){bv,bv,bv,bv};
    }
    const int arow = mt*16 + l15;
    const int aswz = (arow & 7) << 3;
    const short* abase = (const short*)Hf + arow*128;
    #pragma unroll
    for (int kt = 0; kt < 4; ++kt){
      bf16x8 aF = *(const bf16x8*)(abase + ((kt*32 + lg*8) ^ aswz));
      #pragma unroll
      for (int nt = 0; nt < 2; ++nt){
        const int n = nh*32 + nt*16 + l15;
        bf16x8 bF = *(const bf16x8*)((const short*)w1b + n*128 + kt*32 + lg*8);
        acc1[nt] = MFMA(aF, bF, acc1[nt]);
      }
    }
    #pragma unroll
    for (int nt = 0; nt < 2; ++nt)
      #pragma unroll
      for (int r = 0; r < 4; ++r){
        const int row = mt*16 + lg*4 + r;
        const int col = nh*32 + nt*16 + l15;
        y1[row*64 + (col ^ ((row & 7) << 3))] = f2b(sigm(acc1[nt][r]));
      }
  }
  __syncthreads();

  // layer 2: [64x64] @ W2^T[64x32] -> sigmoid -> y2 (fp32, padded 33)
  if (w < 4){
    f32x4 acc2[2];
    #pragma unroll
    for (int nt = 0; nt < 2; ++nt){
      float bv = b2[nt*16 + l15];
      acc2[nt] = (f32x4){bv,bv,bv,bv};
    }
    const int arow = w*16 + l15;
    const int aswz = (arow & 7) << 3;
    const short* abase = (const short*)y1 + arow*64;
    #pragma unroll
    for (int kt = 0; kt < 2; ++kt){
      bf16x8 aF = *(const bf16x8*)(abase + ((kt*32 + lg*8) ^ aswz));
      #pragma unroll
      for (int nt = 0; nt < 2; ++nt){
        const int n = nt*16 + l15;
        bf16x8 bF = *(const bf16x8*)((const short*)w2b + n*64 + kt*32 + lg*8);
        acc2[nt] = MFMA(aF, bF, acc2[nt]);
      }
    }
    #pragma unroll
    for (int nt = 0; nt < 2; ++nt)
      #pragma unroll
      for (int r = 0; r < 4; ++r){
        const int row = w*16 + lg*4 + r;
        const int col = nt*16 + l15;
        y2[row*33 + col] = sigm(acc2[nt][r]);
      }
  }
  __syncthreads();

  // layer 3: [64x32] @ W3^T[32x2] + b3, fp32 vector
  if (tid < 128){
    const int lr = tid >> 1, oc = tid & 1;
    float s = b3[oc];
    #pragma unroll
    for (int k = 0; k < 32; ++k)
      s += y2[lr*33 + k] * W3[oc*32 + k];
    out[(size_t)(r0 + lr)*2 + oc] = s;
  }
}

extern "C" void kernel_launch(void* const* d_in, const int* in_sizes, int n_in,
                              void* d_out, int out_size, void* d_ws, size_t ws_size,
                              hipStream_t stream){
  const int*   x    = (const int*)  d_in[0];
  const float* emb  = (const float*)d_in[1];
  const float* W_ih = (const float*)d_in[2];
  const float* W_hh = (const float*)d_in[3];
  const float* b_ih = (const float*)d_in[4];
  const float* b_hh = (const float*)d_in[5];
  const float* W1   = (const float*)d_in[6];
  const float* b1   = (const float*)d_in[7];
  const float* W2   = (const float*)d_in[8];
  const float* b2   = (const float*)d_in[9];
  const float* W3   = (const float*)d_in[10];
  const float* b3   = (const float*)d_in[11];
  float* out = (float*)d_out;

  const int B = in_sizes[0] / TSTEP;

  ushort* wcomb = (ushort*)d_ws;
  ushort* w1b   = wcomb + 512*KCOMB;
  ushort* w2b   = w1b + 64*128;

  const int prep_total = 512*KCOMB + 64*128 + 32*64;
  prep_kernel<<<(prep_total + 255)/256, 256, 0, stream>>>(W_ih, W_hh, W1, W2, wcomb, w1b, w2b);
  lstm_kernel<<<B/BROWS, 512, 0, stream>>>(x, emb, b_ih, b_hh, b1, b2, W3, b3,
                                           wcomb, w1b, w2b, out);
}

// Round 4
// 377.222 us; speedup vs baseline: 1.9048x; 1.3661x over previous
//
#include <hip/hip_runtime.h>
#include <hip/hip_bf16.h>

#define TSTEP 14
#define BROWS 64          // batch rows per block (8 waves: full 128-col coverage)
#define KCOMB 160         // 128 (h) + 16 (emb) + 16 (zero)
#define ESTR  16          // E row stride in shorts
#define L2E   1.4426950408889634f
#define L2E2  2.8853900817779268f

typedef __attribute__((ext_vector_type(8))) short bf16x8;
typedef __attribute__((ext_vector_type(4))) float f32x4;
typedef __attribute__((ext_vector_type(4))) int   i32x4;

#define MFMA(a,b,c) __builtin_amdgcn_mfma_f32_16x16x32_bf16((a),(b),(c),0,0,0)

__device__ inline ushort f2b(float f){
  union { float f; unsigned u; } v; v.f = f;
  unsigned r = v.u + 0x7fff + ((v.u >> 16) & 1);   // RNE to bf16
  return (ushort)(r >> 16);
}
__device__ inline float rcpf(float x){ return __builtin_amdgcn_rcpf(x); }

#if __has_builtin(__builtin_amdgcn_exp2f)
__device__ inline float EXP2(float x){ return __builtin_amdgcn_exp2f(x); }
#else
__device__ inline float EXP2(float x){ return __expf(x * 0.6931471805599453f); }
#endif

// packed f32x2 -> bf16x2 (RNE), 1 instr
__device__ inline unsigned cvt_pk_bf16(float lo, float hi){
  unsigned r;
  asm("v_cvt_pk_bf16_f32 %0, %1, %2" : "=v"(r) : "v"(lo), "v"(hi));
  return r;
}

// ---- prep: bf16 weight repack, pre-scaled by log2(e) for exp2 activations ---
// wcomb[n][k], n<512, k<160: k<128 -> W_hh; k<144 -> W_ih; else 0.
// rows of gate g (n>>7==2) scaled by 2*log2e (tanh), others by log2e (sigmoid).
__global__ void prep_kernel(const float* __restrict__ W_ih, const float* __restrict__ W_hh,
                            const float* __restrict__ W1,   const float* __restrict__ W2,
                            ushort* __restrict__ wcomb, ushort* __restrict__ w1b, ushort* __restrict__ w2b){
  int i = blockIdx.x * blockDim.x + threadIdx.x;
  if (i < 512*KCOMB){
    int n = i / KCOMB, k = i - n*KCOMB;
    float s = ((n >> 7) == 2) ? L2E2 : L2E;
    float v = (k < 128) ? W_hh[n*128 + k]*s : ((k < 144) ? W_ih[n*16 + (k-128)]*s : 0.f);
    wcomb[i] = f2b(v);
  } else if (i < 512*KCOMB + 64*128){
    int j = i - 512*KCOMB;
    w1b[j] = f2b(W1[j] * L2E);
  } else if (i < 512*KCOMB + 64*128 + 32*64){
    int j = i - 512*KCOMB - 64*128;
    w2b[j] = f2b(W2[j] * L2E);
  }
}

// ---- main fused kernel ---------------------------------------------------
// 8 waves forced: each wave owns cols w*16..w*16+15 of ALL 4 gates (cell
// update is lane-local).  2 waves/SIMD pinned -> 256-reg budget, no spills.
__global__ __attribute__((amdgpu_flat_work_group_size(512, 512), amdgpu_waves_per_eu(2, 2)))
void lstm_kernel(const int* __restrict__ x, const float* __restrict__ emb_table,
                 const float* __restrict__ b_ih, const float* __restrict__ b_hh,
                 const float* __restrict__ b1, const float* __restrict__ b2,
                 const float* __restrict__ W3, const float* __restrict__ b3,
                 const ushort* __restrict__ wcomb, const ushort* __restrict__ w1b,
                 const ushort* __restrict__ w2b, float* __restrict__ out)
{
  __shared__ ushort A_h[2*BROWS*128];                       // 32 KB dbuf h, swizzled
  __shared__ __align__(16) char Ebuf[TSTEP*BROWS*ESTR*2];   // 28.7 KB emb; head aliases

  ushort* E  = (ushort*)Ebuf;
  ushort* y1 = (ushort*)Ebuf;               // [64][64] bf16, swizzled (head reuse)
  float*  y2 = (float*)(Ebuf + 8192);       // [64][33] fp32, padded   (head reuse)

  const int tid  = threadIdx.x;
  const int lane = tid & 63;
  const int w    = tid >> 6;      // wave 0..7
  const int l15  = lane & 15;
  const int lg   = lane >> 4;     // 0..3 (k-group)
  const int r0   = blockIdx.x * BROWS;

  // --- zero init h buffer 0 (16 KB) ---
  { i32x4* az = (i32x4*)A_h;
    #pragma unroll
    for (int i = 0; i < 2; ++i) az[tid + i*512] = (i32x4){0,0,0,0}; }

  // --- stage embeddings (padding_idx=0 -> zeros); halves XOR'd by (r>>2)&1 ---
  for (int idx = tid; idx < BROWS*TSTEP; idx += 512){
    int r = idx / TSTEP, t = idx - r*TSTEP;
    int tok = x[(r0 + r)*TSTEP + t];
    int xr  = (r >> 2) & 1;
    unsigned* dst = (unsigned*)(E + (t*BROWS + r)*ESTR);
    if (tok == 0){
      #pragma unroll
      for (int e = 0; e < 8; ++e) dst[e] = 0u;
    } else {
      const float* src = emb_table + tok*16;
      #pragma unroll
      for (int e = 0; e < 8; ++e)
        dst[((e >> 2) ^ xr)*4 + (e & 3)] = cvt_pk_bf16(src[2*e], src[2*e+1]);
    }
  }

  // --- persistent B fragments: Wcomb[n][k], n = g*128 + w*16 + l15 ---
  bf16x8 bB[4][5];
  #pragma unroll
  for (int g = 0; g < 4; ++g){
    const int n = g*128 + w*16 + l15;
    #pragma unroll
    for (int kt = 0; kt < 5; ++kt)
      bB[g][kt] = *(const bf16x8*)((const short*)wcomb + n*KCOMB + kt*32 + lg*8);
  }

  // --- scaled bias splats (persistent, seed MFMA C) ---
  f32x4 biasv[4];
  #pragma unroll
  for (int g = 0; g < 4; ++g){
    const int n = g*128 + w*16 + l15;
    float bv = (b_ih[n] + b_hh[n]) * ((g == 2) ? L2E2 : L2E);
    biasv[g] = (f32x4){bv,bv,bv,bv};
  }

  // --- cell state fp32: rows (m*16 + lg*4 + r), col w*16+l15 ---
  f32x4 cst[4];
  #pragma unroll
  for (int m = 0; m < 4; ++m) cst[m] = (f32x4){0.f,0.f,0.f,0.f};

  const int j2 = w*16 + l15;

  __syncthreads();   // zero-init + E visible

  // ================= recurrence: 1 barrier/step, dbuf h ==================
  for (int t = 0; t < TSTEP; ++t){
    const ushort* Ar = A_h + (t & 1)*BROWS*128;
    ushort*       Aw = A_h + ((t & 1)^1)*BROWS*128;

    #pragma unroll
    for (int m = 0; m < 4; ++m){
      const int row = m*16 + l15;
      const int swz = (row & 7) << 3;
      const short* base_e = (const short*)Ar + row*128 + ((lg*8) ^ swz);
      const short* base_o = (const short*)Ar + row*128 + ((32 + lg*8) ^ swz);
      bf16x8 aF[5];
      aF[0] = *(const bf16x8*)(base_e);
      aF[1] = *(const bf16x8*)(base_o);
      aF[2] = *(const bf16x8*)(base_e + 64);
      aF[3] = *(const bf16x8*)(base_o + 64);
      // emb k-tile: wcomb rows k=144..159 are zero, so lanes lg>=2 may read
      // any valid half; half-select XOR'd by (row>>2)&1 to spread banks
      aF[4] = *(const bf16x8*)((const short*)E + (t*BROWS + row)*ESTR
                               + (((lg & 1) ^ ((row >> 2) & 1))*8));

      f32x4 acc[4];
      #pragma unroll
      for (int g = 0; g < 4; ++g){
        acc[g] = MFMA(aF[0], bB[g][0], biasv[g]);
        #pragma unroll
        for (int kt = 1; kt < 5; ++kt)
          acc[g] = MFMA(aF[kt], bB[g][kt], acc[g]);
      }

      // --- cell update + h write (exp2-based activations, pre-scaled) ---
      #pragma unroll
      for (int rp = 0; rp < 2; ++rp){
        float h2[2];
        #pragma unroll
        for (int q = 0; q < 2; ++q){
          const int r = rp*2 + q;
          float iv = rcpf(1.f + EXP2(-acc[0][r]));
          float fv = rcpf(1.f + EXP2(-acc[1][r]));
          float gv = __builtin_fmaf(-2.f, rcpf(EXP2(acc[2][r]) + 1.f), 1.f);
          float ov = rcpf(1.f + EXP2(-acc[3][r]));
          float cv = __builtin_fmaf(fv, cst[m][r], iv*gv);
          cst[m][r] = cv;
          h2[q] = ov * __builtin_fmaf(-2.f, rcpf(EXP2(cv*L2E2) + 1.f), 1.f);
        }
        unsigned u = cvt_pk_bf16(h2[0], h2[1]);
        const int row0 = m*16 + lg*4 + rp*2;
        const int row1 = row0 + 1;
        Aw[row0*128 + (j2 ^ ((row0 & 7) << 3))] = (ushort)u;
        Aw[row1*128 + (j2 ^ ((row1 & 7) << 3))] = (ushort)(u >> 16);
      }
    }

    __syncthreads();   // Aw visible; everyone done reading Ar
  }

  // h_last is in buffer 0 (14 toggles)
  const ushort* Hf = A_h;

  // ================= MLP head =================
  // layer 1: [64x128] @ W1^T -> sigmoid -> y1 (bf16, swizzled). mt=w&3, nh=w>>2
  {
    const int mt = w & 3, nh = w >> 2;
    f32x4 acc1[2];
    #pragma unroll
    for (int nt = 0; nt < 2; ++nt){
      float bv = b1[nh*32 + nt*16 + l15] * L2E;
      acc1[nt] = (f32x4){bv,bv,bv,bv};
    }
    const int arow = mt*16 + l15;
    const int aswz = (arow & 7) << 3;
    const short* abase = (const short*)Hf + arow*128;
    #pragma unroll
    for (int kt = 0; kt < 4; ++kt){
      bf16x8 aF = *(const bf16x8*)(abase + ((kt*32 + lg*8) ^ aswz));
      #pragma unroll
      for (int nt = 0; nt < 2; ++nt){
        const int n = nh*32 + nt*16 + l15;
        bf16x8 bF = *(const bf16x8*)((const short*)w1b + n*128 + kt*32 + lg*8);
        acc1[nt] = MFMA(aF, bF, acc1[nt]);
      }
    }
    #pragma unroll
    for (int nt = 0; nt < 2; ++nt)
      #pragma unroll
      for (int r = 0; r < 4; ++r){
        const int row = mt*16 + lg*4 + r;
        const int col = nh*32 + nt*16 + l15;
        y1[row*64 + (col ^ ((row & 7) << 3))] = f2b(rcpf(1.f + EXP2(-acc1[nt][r])));
      }
  }
  __syncthreads();

  // layer 2: [64x64] @ W2^T -> sigmoid -> y2 (fp32, stride 33). waves 0..3
  if (w < 4){
    f32x4 acc2[2];
    #pragma unroll
    for (int nt = 0; nt < 2; ++nt){
      float bv = b2[nt*16 + l15] * L2E;
      acc2[nt] = (f32x4){bv,bv,bv,bv};
    }
    const int arow = w*16 + l15;
    const int aswz = (arow & 7) << 3;
    const short* abase = (const short*)y1 + arow*64;
    #pragma unroll
    for (int kt = 0; kt < 2; ++kt){
      bf16x8 aF = *(const bf16x8*)(abase + ((kt*32 + lg*8) ^ aswz));
      #pragma unroll
      for (int nt = 0; nt < 2; ++nt){
        const int n = nt*16 + l15;
        bf16x8 bF = *(const bf16x8*)((const short*)w2b + n*64 + kt*32 + lg*8);
        acc2[nt] = MFMA(aF, bF, acc2[nt]);
      }
    }
    #pragma unroll
    for (int nt = 0; nt < 2; ++nt)
      #pragma unroll
      for (int r = 0; r < 4; ++r){
        const int row = w*16 + lg*4 + r;
        const int col = nt*16 + l15;
        y2[row*33 + col] = rcpf(1.f + EXP2(-acc2[nt][r]));
      }
  }
  __syncthreads();

  // layer 3: [64x32] @ W3^T[32x2] + b3, fp32 vector (128 threads)
  if (tid < 128){
    const int lr = tid >> 1, oc = tid & 1;
    float s = b3[oc];
    #pragma unroll
    for (int k = 0; k < 32; ++k)
      s += y2[lr*33 + k] * W3[oc*32 + k];
    out[(size_t)(r0 + lr)*2 + oc] = s;
  }
}

extern "C" void kernel_launch(void* const* d_in, const int* in_sizes, int n_in,
                              void* d_out, int out_size, void* d_ws, size_t ws_size,
                              hipStream_t stream){
  const int*   x    = (const int*)  d_in[0];
  const float* emb  = (const float*)d_in[1];
  const float* W_ih = (const float*)d_in[2];
  const float* W_hh = (const float*)d_in[3];
  const float* b_ih = (const float*)d_in[4];
  const float* b_hh = (const float*)d_in[5];
  const float* W1   = (const float*)d_in[6];
  const float* b1   = (const float*)d_in[7];
  const float* W2   = (const float*)d_in[8];
  const float* b2   = (const float*)d_in[9];
  const float* W3   = (const float*)d_in[10];
  const float* b3   = (const float*)d_in[11];
  float* out = (float*)d_out;

  const int B = in_sizes[0] / TSTEP;

  ushort* wcomb = (ushort*)d_ws;
  ushort* w1b   = wcomb + 512*KCOMB;
  ushort* w2b   = w1b + 64*128;

  const int prep_total = 512*KCOMB + 64*128 + 32*64;
  prep_kernel<<<(prep_total + 255)/256, 256, 0, stream>>>(W_ih, W_hh, W1, W2, wcomb, w1b, w2b);
  lstm_kernel<<<B/BROWS, 512, 0, stream>>>(x, emb, b_ih, b_hh, b1, b2, W3, b3,
                                           wcomb, w1b, w2b, out);
}